// Round 5
// baseline (4697.218 us; speedup 1.0000x reference)
//
#include <hip/hip_runtime.h>
#include <stdint.h>
#include <math.h>

#define NPTS  8192
#define NB    2
#define NC    64
#define MCENT 2048
#define HH    128
#define K2NN  32
#define S1STR 132
#define GRID  256
#define PUBMASK 7

// float offsets inside d_out (outputs concatenated flat, all read as fp32)
#define OUT0_OFF 0                                   // dsamp_xyz (B,M,3)
#define OUT1_OFF (NB*MCENT*3)                        // shifted   (B,2M,3)
#define OUT2_OFF (OUT1_OFF + NB*2*MCENT*3)           // feats     (B,2*O,M)
#define OUT3_OFF (OUT2_OFF + NB*2*HH*MCENT)          // idx       (B,M) as float

// LDS union layout (bytes). FPS role: xs/ys/zs mirror + warr.
// Consumer role: d2u (KNN) overlapped by s1/s2 (EGNN, after KNN done).
#define SM_SIZE  98432
#define SM_XS    0
#define SM_YS    32768
#define SM_ZS    65536
#define SM_FWARR 98304
#define SM_D2U   0
#define SM_S1    0
#define SM_S2    16896
#define SM_HJ    33792
#define SM_HI    41984
#define SM_REL   42240
#define SM_D2S   42624
#define SM_AGG   42752
#define SM_T1    43264
#define SM_COEF  43776
#define SM_NIDX  43904
#define SM_CWARR 44032

__device__ __forceinline__ float silu_f(float v){ return v / (1.0f + expf(-v)); }

// ---- fast wave-wide u32 butterfly reduce: 4x DPP + swizzle(xor16) + shfl(xor32)
template<int CTRL>
__device__ __forceinline__ unsigned dppmov(unsigned v){
  return (unsigned)__builtin_amdgcn_update_dpp(0, (int)v, CTRL, 0xF, 0xF, true);
}
__device__ __forceinline__ unsigned wave_min_u32(unsigned v){
  unsigned s;
  s = dppmov<0xB1>(v);  v = v < s ? v : s;   // xor1
  s = dppmov<0x4E>(v);  v = v < s ? v : s;   // xor2
  s = dppmov<0x141>(v); v = v < s ? v : s;   // xor4
  s = dppmov<0x140>(v); v = v < s ? v : s;   // xor8
  s = (unsigned)__builtin_amdgcn_ds_swizzle((int)v, 0x401F); v = v < s ? v : s; // xor16
  s = (unsigned)__shfl_xor((int)v, 32); v = v < s ? v : s;                      // xor32
  return v;
}

// ---------------------------------------------------------------------------
// FPS (blocks 0..1): round-2 proven body. 512 thr x 16 pts in registers,
// LDS mirror for winner broadcast, one barrier/iter, u64 (val, N-1-p) argmax
// (exact reference semantics: contract off, numpy op order, first-max index).
// Publishes progress (centers done) every 8 iters with agent-release.
// ---------------------------------------------------------------------------
__device__ void fps_block(const int b, const int tid,
                          const float* __restrict__ xyz,
                          float* __restrict__ out,
                          int* __restrict__ ws_idx,
                          int* __restrict__ prog,
                          char* smem)
{
#pragma clang fp contract(off)
  float* xs = (float*)(smem + SM_XS);
  float* ys = (float*)(smem + SM_YS);
  float* zs = (float*)(smem + SM_ZS);
  unsigned long long (*warr)[8] = (unsigned long long (*)[8])(smem + SM_FWARR);
  const float* P = xyz + (size_t)b * NPTS * 3;

  float x[16], y[16], z[16], mind[16];
  #pragma unroll
  for (int j = 0; j < 16; ++j){
    const int p = tid*16 + j;
    const float px = P[p*3+0], py = P[p*3+1], pz = P[p*3+2];
    x[j]=px; y[j]=py; z[j]=pz; mind[j]=1e10f;
    xs[p]=px; ys[p]=py; zs[p]=pz;
  }
  float cx = P[0], cy = P[1], cz = P[2];
  if (tid == 0){
    ws_idx[b*MCENT] = 0;
    out[OUT3_OFF + b*MCENT] = 0.0f;
    out[OUT0_OFF + (size_t)(b*MCENT)*3+0] = cx;
    out[OUT0_OFF + (size_t)(b*MCENT)*3+1] = cy;
    out[OUT0_OFF + (size_t)(b*MCENT)*3+2] = cz;
  }
  __syncthreads();

  for (int t = 1; t < MCENT; ++t){
    float bestv = -1.0f; int bestp = tid*16;
    #pragma unroll
    for (int j = 0; j < 16; ++j){
      const float dx = x[j]-cx, dy = y[j]-cy, dz = z[j]-cz;
      const float d  = (dx*dx + dy*dy) + dz*dz;   // contract off: per-op rounding
      const float mn = fminf(mind[j], d);
      mind[j] = mn;
      if (mn > bestv){ bestv = mn; bestp = tid*16 + j; }
    }
    unsigned long long key = ((unsigned long long)__float_as_uint(bestv) << 32)
                           | (unsigned)(NPTS - 1 - bestp);
    #pragma unroll
    for (int o = 32; o > 0; o >>= 1){
      const unsigned long long k2 = __shfl_xor(key, o);
      if (k2 > key) key = k2;
    }
    if ((tid & 63) == 0) warr[t & 1][tid >> 6] = key;
    __syncthreads();
    unsigned long long kb = warr[t & 1][0];
    #pragma unroll
    for (int w = 1; w < 8; ++w){
      const unsigned long long k2 = warr[t & 1][w];
      if (k2 > kb) kb = k2;                        // ties -> larger (N-1-p) = smaller p
    }
    const int p = NPTS - 1 - (int)(kb & 0xFFFFFFFFULL);
    cx = xs[p]; cy = ys[p]; cz = zs[p];
    if (tid == 0){
      ws_idx[b*MCENT + t] = p;
      out[OUT3_OFF + b*MCENT + t] = (float)p;
      out[OUT0_OFF + (size_t)(b*MCENT+t)*3+0] = cx;
      out[OUT0_OFF + (size_t)(b*MCENT+t)*3+1] = cy;
      out[OUT0_OFF + (size_t)(b*MCENT+t)*3+2] = cz;
      if (((t+1) & PUBMASK) == 0)
        __hip_atomic_store(&prog[b*64], t+1, __ATOMIC_RELEASE, __HIP_MEMORY_SCOPE_AGENT);
    }
  }
}

// ---------------------------------------------------------------------------
// KNN (consumer phase 1): exact 32-NN ascending by (d2, idx), 512 threads,
// per-thread top-2 cache, double-buffered warr (one barrier/iter).
// Writes the 32 neighbor indices into LDS nidx[].
// ---------------------------------------------------------------------------
__device__ void knn512(const int b, const int m, const int tid,
                       const float* __restrict__ xyz,
                       const float* __restrict__ out,
                       char* smem)
{
#pragma clang fp contract(off)
  unsigned* d2u = (unsigned*)(smem + SM_D2U);
  unsigned long long (*warr)[8] = (unsigned long long (*)[8])(smem + SM_CWARR);
  int* nidx = (int*)(smem + SM_NIDX);
  const float* P = xyz + (size_t)b*NPTS*3;
  const float cx = out[OUT0_OFF + (size_t)(b*MCENT+m)*3+0];
  const float cy = out[OUT0_OFF + (size_t)(b*MCENT+m)*3+1];
  const float cz = out[OUT0_OFF + (size_t)(b*MCENT+m)*3+2];
  const float cn = (cx*cx + cy*cy) + cz*cz;

  unsigned long long best=~0ULL, second=~0ULL;
  #pragma unroll 4
  for (int j = 0; j < NPTS/512; ++j){
    const int p = tid + 512*j;
    const float px=P[p*3+0], py=P[p*3+1], pz=P[p*3+2];
    const float pn=(px*px+py*py)+pz*pz;
    const float e =(cx*px+cy*py)+cz*pz;
    const float d2=(cn+pn)-2.0f*e;                 // reference formula / op order
    unsigned u = __float_as_uint(d2);
    u = (u & 0x80000000u) ? ~u : (u | 0x80000000u);
    d2u[p] = u;
    const unsigned long long kk = ((unsigned long long)u<<32) | (unsigned)p;
    if (kk < best){ second = best; best = kk; }
    else if (kk < second){ second = kk; }
  }
  __syncthreads();

  for (int it = 0; it < K2NN; ++it){
    const unsigned vb = (unsigned)(best>>32);
    const unsigned wv = wave_min_u32(vb);
    const unsigned long long bal = __ballot(vb == wv);
    unsigned long long k;
    if (__popcll(bal) == 1){
      const int lane = __ffsll(bal)-1;
      const unsigned lp = (unsigned)__shfl((int)(unsigned)best, lane);  // low32 = p
      k = ((unsigned long long)wv<<32) | lp;
    } else {
      k = best;                                     // exact u64 fallback (rare tie)
      #pragma unroll
      for (int o = 32; o > 0; o >>= 1){
        const unsigned long long k2 = __shfl_xor(k, o);
        if (k2 < k) k = k2;
      }
    }
    if ((tid & 63) == 0) warr[it & 1][tid >> 6] = k;
    __syncthreads();
    unsigned long long kb = warr[it & 1][tid & 7];
    #pragma unroll
    for (int o = 4; o > 0; o >>= 1){
      const unsigned long long k2 = __shfl_xor(kb, o);
      if (k2 < kb) kb = k2;                        // u64 min: ties pick min p
    }
    const unsigned p = (unsigned)kb;
    if (tid == 0) nidx[it] = (int)p;
    if (best == kb){                               // unique owner (keys unique by p)
      d2u[p] = 0xFFFFFFFFu;
      best = second; second = ~0ULL;
      if (best == ~0ULL){                          // top-2 exhausted: rescan own part
        #pragma unroll 4
        for (int j = 0; j < NPTS/512; ++j){
          const int q = tid + 512*j;
          const unsigned long long kk = ((unsigned long long)d2u[q]<<32)|(unsigned)q;
          if (kk < best){ second = best; best = kk; }
          else if (kk < second){ second = kk; }
        }
      }
    }
  }
  __syncthreads();   // nidx visible to staging
}

// ---------------------------------------------------------------------------
// EGNN per-scale (consumer phase 2), 512 threads: h = tid&127, 4 j-groups.
// ---------------------------------------------------------------------------
template<int KNB>
__device__ void egnn_scale512(const int isc, const int b, const int m, const int tid,
    const float* __restrict__ we1, const float* __restrict__ be1,
    const float* __restrict__ we2, const float* __restrict__ be2,
    const float* __restrict__ wxw, const float* __restrict__ bxw,
    const float* __restrict__ wh1, const float* __restrict__ bh1,
    const float* __restrict__ wh2, const float* __restrict__ bh2,
    const float* hi, const float (*hj)[NC], const float (*rel)[3], const float* d2s,
    float (*s1)[S1STR], float (*s2)[S1STR], float* coefs, float* aggs, float* t1,
    const float cx, const float cy, const float cz, float* __restrict__ out)
{
  constexpr int KH = KNB/4;
  const int h  = tid & 127;
  const int jg = tid >> 7;            // 0..3
  const int j0 = jg * KH;
  const float* W1 = we1 + (size_t)isc*(2*NC+1)*HH;
  const float* W2 = we2 + (size_t)isc*HH*HH;

  // ---- edge layer 1: [h_i, h_j, d2] @ we1 + be1, silu (h_i dot shared over j)
  float shi = be1[isc*HH + h];
  for (int r = 0; r < NC; ++r) shi += hi[r]*W1[r*HH + h];
  float acc[KH];
  #pragma unroll
  for (int jl = 0; jl < KH; ++jl) acc[jl] = shi;
  for (int r4 = 0; r4 < NC/4; ++r4){
    const float w0 = W1[(NC+4*r4+0)*HH+h];
    const float w1 = W1[(NC+4*r4+1)*HH+h];
    const float w2 = W1[(NC+4*r4+2)*HH+h];
    const float w3 = W1[(NC+4*r4+3)*HH+h];
    #pragma unroll
    for (int jl = 0; jl < KH; ++jl){
      const float4 v = *(const float4*)&hj[j0+jl][4*r4];
      acc[jl] += v.x*w0; acc[jl] += v.y*w1; acc[jl] += v.z*w2; acc[jl] += v.w*w3;
    }
  }
  {
    const float wd = W1[2*NC*HH + h];
    #pragma unroll
    for (int jl = 0; jl < KH; ++jl)
      s1[j0+jl][h] = silu_f(acc[jl] + d2s[j0+jl]*wd);
  }
  __syncthreads();

  // ---- edge layer 2
  float acc2[KH];
  { const float b2 = be2[isc*HH+h];
    #pragma unroll
    for (int jl=0;jl<KH;++jl) acc2[jl]=b2; }
  for (int r4 = 0; r4 < HH/4; ++r4){
    const float w0 = W2[(4*r4+0)*HH+h];
    const float w1 = W2[(4*r4+1)*HH+h];
    const float w2 = W2[(4*r4+2)*HH+h];
    const float w3 = W2[(4*r4+3)*HH+h];
    #pragma unroll
    for (int jl=0;jl<KH;++jl){
      const float4 v = *(const float4*)&s1[j0+jl][4*r4];
      acc2[jl]+=v.x*w0; acc2[jl]+=v.y*w1; acc2[jl]+=v.z*w2; acc2[jl]+=v.w*w3;
    }
  }
  #pragma unroll
  for (int jl=0;jl<KH;++jl) s2[j0+jl][h] = silu_f(acc2[jl]);
  __syncthreads();

  // ---- agg (tid<128) and coef per j (tid 128..128+KNB)
  if (tid < HH){
    float a = 0.f;
    #pragma unroll
    for (int j = 0; j < KNB; ++j) a += s2[j][tid];
    aggs[tid] = a;
  } else if (tid < HH + KNB){
    const int j = tid - HH;
    const float* WX = wxw + isc*HH;
    float c = 0.f;
    for (int r = 0; r < HH; ++r) c += s2[j][r]*WX[r];
    coefs[j] = c + bxw[isc];
  }
  __syncthreads();

  if (tid < 3){
    float s = 0.f;
    #pragma unroll
    for (int j = 0; j < KNB; ++j) s += rel[j][tid]*coefs[j];
    const float cc = (tid==0)?cx:((tid==1)?cy:cz);
    out[OUT1_OFF + ((size_t)(b*2+isc)*MCENT + m)*3 + tid] = cc + s*(1.0f/KNB);
  }
  if (tid < HH){
    const float* WH1 = wh1 + (size_t)isc*(NC+HH)*HH;
    float n = bh1[isc*HH + tid];
    for (int r = 0; r < NC; ++r) n += hi[r]*WH1[r*HH+tid];
    for (int r = 0; r < HH; ++r) n += aggs[r]*WH1[(NC+r)*HH+tid];
    t1[tid] = silu_f(n);
  }
  __syncthreads();
  if (tid < HH){
    const float* WH2 = wh2 + (size_t)isc*HH*HH;
    float v = bh2[isc*HH + tid];
    for (int r = 0; r < HH; ++r) v += t1[r]*WH2[r*HH+tid];
    out[OUT2_OFF + ((size_t)(b*2*HH) + isc*HH + tid)*MCENT + m] = v;
  }
  __syncthreads();   // before smem reuse by next scale / next item
}

// ---------------------------------------------------------------------------
// Consumer blocks 2..255: poll progress, then KNN + EGNN for each (b,m) item.
// ---------------------------------------------------------------------------
__device__ void consumer_block(const int tid,
    const float* __restrict__ xyz, const float* __restrict__ feat,
    const float* __restrict__ we1, const float* __restrict__ be1,
    const float* __restrict__ we2, const float* __restrict__ be2,
    const float* __restrict__ wxw, const float* __restrict__ bxw,
    const float* __restrict__ wh1, const float* __restrict__ bh1,
    const float* __restrict__ wh2, const float* __restrict__ bh2,
    const int* __restrict__ ws_idx, int* __restrict__ prog,
    float* __restrict__ out, char* smem)
{
  float (*s1)[S1STR] = (float (*)[S1STR])(smem + SM_S1);
  float (*s2)[S1STR] = (float (*)[S1STR])(smem + SM_S2);
  float (*hj)[NC]    = (float (*)[NC])(smem + SM_HJ);
  float* hi    = (float*)(smem + SM_HI);
  float (*rel)[3] = (float (*)[3])(smem + SM_REL);
  float* d2s   = (float*)(smem + SM_D2S);
  float* aggs  = (float*)(smem + SM_AGG);
  float* t1    = (float*)(smem + SM_T1);
  float* coefs = (float*)(smem + SM_COEF);
  int* nidx    = (int*)(smem + SM_NIDX);

  const int nitems = NB*MCENT;
  for (int item = (int)blockIdx.x - NB; item < nitems; item += (int)gridDim.x - NB){
    const int b = item >> 11;
    const int m = item & (MCENT-1);
    if (tid == 0){
      long spins = 0;
      for (;;){
        const int pv = __hip_atomic_load(&prog[b*64], __ATOMIC_ACQUIRE,
                                         __HIP_MEMORY_SCOPE_AGENT);
        if (pv >= m+1) break;
        if (m+1-pv > 64) __builtin_amdgcn_s_sleep(64);
        else             __builtin_amdgcn_s_sleep(4);
        if (++spins > 60000000L) break;   // bail-out: never expected, avoids hang
      }
    }
    __syncthreads();                       // acquire by tid0 covers block (same CU/L1)

    knn512(b, m, tid, xyz, out, smem);

    const float* P = xyz + (size_t)b*NPTS*3;
    const float cx = out[OUT0_OFF + (size_t)(b*MCENT+m)*3+0];
    const float cy = out[OUT0_OFF + (size_t)(b*MCENT+m)*3+1];
    const float cz = out[OUT0_OFF + (size_t)(b*MCENT+m)*3+2];
    const int ci = ws_idx[b*MCENT + m];
    if (tid < NC) hi[tid] = feat[((size_t)b*NC + tid)*NPTS + ci];
    if (tid < K2NN){
      const int p = nidx[tid];
      const float rx = cx - P[p*3+0];
      const float ry = cy - P[p*3+1];
      const float rz = cz - P[p*3+2];
      rel[tid][0]=rx; rel[tid][1]=ry; rel[tid][2]=rz;
      d2s[tid] = rx*rx + ry*ry + rz*rz;
    }
    {
      const int j  = tid >> 4;             // 0..31
      const int c0 = (tid & 15) * 4;
      const int p  = nidx[j];
      #pragma unroll
      for (int q = 0; q < 4; ++q)
        hj[j][c0+q] = feat[((size_t)b*NC + c0 + q)*NPTS + p];
    }
    __syncthreads();

    egnn_scale512<16>(0, b, m, tid, we1,be1,we2,be2,wxw,bxw,wh1,bh1,wh2,bh2,
                      hi, hj, rel, d2s, s1, s2, coefs, aggs, t1, cx, cy, cz, out);
    egnn_scale512<32>(1, b, m, tid, we1,be1,we2,be2,wxw,bxw,wh1,bh1,wh2,bh2,
                      hi, hj, rel, d2s, s1, s2, coefs, aggs, t1, cx, cy, cz, out);
  }
}

// ---------------------------------------------------------------------------
__global__ __launch_bounds__(512, 2) void fused_kernel(
    const float* __restrict__ xyz, const float* __restrict__ feat,
    const float* __restrict__ we1, const float* __restrict__ be1,
    const float* __restrict__ we2, const float* __restrict__ be2,
    const float* __restrict__ wxw, const float* __restrict__ bxw,
    const float* __restrict__ wh1, const float* __restrict__ bh1,
    const float* __restrict__ wh2, const float* __restrict__ bh2,
    int* __restrict__ ws_idx, int* __restrict__ prog,
    float* __restrict__ out)
{
  __shared__ __align__(16) char smem[SM_SIZE];
  const int tid = threadIdx.x;
  if (blockIdx.x < NB){
    fps_block((int)blockIdx.x, tid, xyz, out, ws_idx, prog, smem);
  } else {
    consumer_block(tid, xyz, feat, we1,be1,we2,be2,wxw,bxw,wh1,bh1,wh2,bh2,
                   ws_idx, prog, out, smem);
  }
}

__global__ void init_kernel(int* __restrict__ prog){
  prog[threadIdx.x] = 0;
}

// ---------------------------------------------------------------------------
extern "C" void kernel_launch(void* const* d_in, const int* in_sizes, int n_in,
                              void* d_out, int out_size, void* d_ws, size_t ws_size,
                              hipStream_t stream){
  const float* xyz = (const float*)d_in[0];
  const float* feat= (const float*)d_in[1];
  const float* we1 = (const float*)d_in[2];
  const float* be1 = (const float*)d_in[3];
  const float* we2 = (const float*)d_in[4];
  const float* be2 = (const float*)d_in[5];
  const float* wxw = (const float*)d_in[6];
  const float* bxw = (const float*)d_in[7];
  const float* wh1 = (const float*)d_in[8];
  const float* bh1 = (const float*)d_in[9];
  const float* wh2 = (const float*)d_in[10];
  const float* bh2 = (const float*)d_in[11];
  float* out = (float*)d_out;

  // workspace: prog[128] ints (padded counters) + ws_idx (B*M ints)
  int* prog   = (int*)d_ws;
  int* ws_idx = prog + 128;

  init_kernel <<<dim3(1),    dim3(128), 0, stream>>>(prog);
  fused_kernel<<<dim3(GRID), dim3(512), 0, stream>>>(xyz, feat,
      we1, be1, we2, be2, wxw, bxw, wh1, bh1, wh2, bh2, ws_idx, prog, out);
}

// Round 6
// 4217.231 us; speedup vs baseline: 1.1138x; 1.1138x over previous
//
#include <hip/hip_runtime.h>
#include <stdint.h>
#include <math.h>

#define NPTS  8192
#define NB    2
#define NC    64
#define MCENT 2048
#define HH    128
#define K2NN  32
#define S1STR 132
#define GRID  256
#define SENT  0xFFFFFFFFu

// float offsets inside d_out (outputs concatenated flat, all read as fp32)
#define OUT0_OFF 0                                   // dsamp_xyz (B,M,3)
#define OUT1_OFF (NB*MCENT*3)                        // shifted   (B,2M,3)
#define OUT2_OFF (OUT1_OFF + NB*2*MCENT*3)           // feats     (B,2*O,M)
#define OUT3_OFF (OUT2_OFF + NB*2*HH*MCENT)          // idx       (B,M) as float

// LDS union layout (bytes). FPS role: xs/ys/zs mirror + warr.
// Consumer role: d2u (KNN) later overlapped by s1/s2 (EGNN), barrier-separated.
#define SM_SIZE  98432
#define SM_XS    0
#define SM_YS    32768
#define SM_ZS    65536
#define SM_FWARR 98304
#define SM_D2U   0
#define SM_S1    0
#define SM_S2    16896
#define SM_HJ    33792
#define SM_HI    41984
#define SM_REL   42240
#define SM_D2S   42624
#define SM_AGG   42752
#define SM_T1    43264
#define SM_COEF  43776
#define SM_NIDX  43904
#define SM_CWARR 44032

__device__ __forceinline__ float silu_f(float v){ return v / (1.0f + expf(-v)); }

// ---- fast wave-wide u32 butterfly reduce: 4x DPP + swizzle(xor16) + shfl(xor32)
template<int CTRL>
__device__ __forceinline__ unsigned dppmov(unsigned v){
  return (unsigned)__builtin_amdgcn_update_dpp(0, (int)v, CTRL, 0xF, 0xF, true);
}
__device__ __forceinline__ unsigned wave_max_u32(unsigned v){
  unsigned s;
  s = dppmov<0xB1>(v);  v = v > s ? v : s;   // xor1
  s = dppmov<0x4E>(v);  v = v > s ? v : s;   // xor2
  s = dppmov<0x141>(v); v = v > s ? v : s;   // half-row mirror
  s = dppmov<0x140>(v); v = v > s ? v : s;   // row mirror
  s = (unsigned)__builtin_amdgcn_ds_swizzle((int)v, 0x401F); v = v > s ? v : s; // xor16
  s = (unsigned)__shfl_xor((int)v, 32); v = v > s ? v : s;                      // xor32
  return v;
}
__device__ __forceinline__ unsigned wave_min_u32(unsigned v){
  unsigned s;
  s = dppmov<0xB1>(v);  v = v < s ? v : s;
  s = dppmov<0x4E>(v);  v = v < s ? v : s;
  s = dppmov<0x141>(v); v = v < s ? v : s;
  s = dppmov<0x140>(v); v = v < s ? v : s;
  s = (unsigned)__builtin_amdgcn_ds_swizzle((int)v, 0x401F); v = v < s ? v : s;
  s = (unsigned)__shfl_xor((int)v, 32); v = v < s ? v : s;
  return v;
}

// ---------------------------------------------------------------------------
// FPS (blocks 0..1): round-2 proven distance/argmax body; wave reduce upgraded
// to DPP u32 value-max + ballot + one shfl (removes the u64 LDS-shuffle chain).
// Publishes winner index per iteration via RELAXED agent atomic store (no
// fences, no cache maintenance). Writes nothing else to global memory.
// Exact reference semantics: contract off, numpy op order, first-max index.
// ---------------------------------------------------------------------------
__device__ void fps_block(const int b, const int tid,
                          const float* __restrict__ xyz,
                          unsigned* __restrict__ pa,
                          char* smem)
{
#pragma clang fp contract(off)
  float* xs = (float*)(smem + SM_XS);
  float* ys = (float*)(smem + SM_YS);
  float* zs = (float*)(smem + SM_ZS);
  unsigned long long (*warr)[8] = (unsigned long long (*)[8])(smem + SM_FWARR);
  const float* P = xyz + (size_t)b * NPTS * 3;

  float x[16], y[16], z[16], mind[16];
  #pragma unroll
  for (int j = 0; j < 16; ++j){
    const int p = tid*16 + j;
    const float px = P[p*3+0], py = P[p*3+1], pz = P[p*3+2];
    x[j]=px; y[j]=py; z[j]=pz; mind[j]=1e10f;
    xs[p]=px; ys[p]=py; zs[p]=pz;
  }
  float cx = P[0], cy = P[1], cz = P[2];
  if (tid == 0)
    __hip_atomic_store(&pa[b*MCENT], 0u, __ATOMIC_RELAXED, __HIP_MEMORY_SCOPE_AGENT);
  __syncthreads();

  for (int t = 1; t < MCENT; ++t){
    float bestv = -1.0f; int bestp = tid*16;
    #pragma unroll
    for (int j = 0; j < 16; ++j){
      const float dx = x[j]-cx, dy = y[j]-cy, dz = z[j]-cz;
      const float d  = (dx*dx + dy*dy) + dz*dz;   // contract off: per-op rounding
      const float mn = fminf(mind[j], d);
      mind[j] = mn;
      if (mn > bestv){ bestv = mn; bestp = tid*16 + j; }  // first-max kept
    }
    // wave-wide value max (bestv >= 0 so u32 order == f32 order), then the
    // lowest tied lane = lowest point index (blocked point assignment).
    const unsigned vb = __float_as_uint(bestv);
    const unsigned wv = wave_max_u32(vb);
    const unsigned long long bal = __ballot(vb == wv);
    const int lane = __ffsll(bal) - 1;
    const int wp   = __shfl(bestp, lane);
    if ((tid & 63) == 0)
      warr[t & 1][tid >> 6] = ((unsigned long long)wv << 32) | (unsigned)(NPTS-1-wp);
    __syncthreads();
    unsigned long long kb = warr[t & 1][0];
    #pragma unroll
    for (int w = 1; w < 8; ++w){
      const unsigned long long k2 = warr[t & 1][w];
      if (k2 > kb) kb = k2;                        // ties -> larger (N-1-p) = smaller p
    }
    const int p = NPTS - 1 - (int)(kb & 0xFFFFFFFFULL);
    cx = xs[p]; cy = ys[p]; cz = zs[p];
    if (tid == 0)
      __hip_atomic_store(&pa[b*MCENT + t], (unsigned)p,
                         __ATOMIC_RELAXED, __HIP_MEMORY_SCOPE_AGENT);
  }
}

// ---------------------------------------------------------------------------
// KNN (consumer phase 1): exact 32-NN ascending by (d2, idx), 512 threads,
// per-thread top-2 cache, double-buffered warr. Center xyz passed in (derived
// from the published index -> no dependence on producer's global writes).
// ---------------------------------------------------------------------------
__device__ void knn512(const int b, const float cx, const float cy, const float cz,
                       const int tid, const float* __restrict__ xyz, char* smem)
{
#pragma clang fp contract(off)
  unsigned* d2u = (unsigned*)(smem + SM_D2U);
  unsigned long long (*warr)[8] = (unsigned long long (*)[8])(smem + SM_CWARR);
  int* nidx = (int*)(smem + SM_NIDX);
  const float* P = xyz + (size_t)b*NPTS*3;
  const float cn = (cx*cx + cy*cy) + cz*cz;

  unsigned long long best=~0ULL, second=~0ULL;
  #pragma unroll 4
  for (int j = 0; j < NPTS/512; ++j){
    const int p = tid + 512*j;
    const float px=P[p*3+0], py=P[p*3+1], pz=P[p*3+2];
    const float pn=(px*px+py*py)+pz*pz;
    const float e =(cx*px+cy*py)+cz*pz;
    const float d2=(cn+pn)-2.0f*e;                 // reference formula / op order
    unsigned u = __float_as_uint(d2);
    u = (u & 0x80000000u) ? ~u : (u | 0x80000000u);
    d2u[p] = u;
    const unsigned long long kk = ((unsigned long long)u<<32) | (unsigned)p;
    if (kk < best){ second = best; best = kk; }
    else if (kk < second){ second = kk; }
  }
  __syncthreads();

  for (int it = 0; it < K2NN; ++it){
    const unsigned vb = (unsigned)(best>>32);
    const unsigned wv = wave_min_u32(vb);
    const unsigned long long bal = __ballot(vb == wv);
    unsigned long long k;
    if (__popcll(bal) == 1){
      const int lane = __ffsll(bal)-1;
      const unsigned lp = (unsigned)__shfl((int)(unsigned)best, lane);  // low32 = p
      k = ((unsigned long long)wv<<32) | lp;
    } else {
      k = best;                                     // exact u64 fallback (rare tie)
      #pragma unroll
      for (int o = 32; o > 0; o >>= 1){
        const unsigned long long k2 = __shfl_xor(k, o);
        if (k2 < k) k = k2;
      }
    }
    if ((tid & 63) == 0) warr[it & 1][tid >> 6] = k;
    __syncthreads();
    unsigned long long kb = warr[it & 1][tid & 7];
    #pragma unroll
    for (int o = 4; o > 0; o >>= 1){
      const unsigned long long k2 = __shfl_xor(kb, o);
      if (k2 < kb) kb = k2;                        // u64 min: ties pick min p
    }
    const unsigned p = (unsigned)kb;
    if (tid == 0) nidx[it] = (int)p;
    if (best == kb){                               // unique owner (keys unique by p)
      d2u[p] = 0xFFFFFFFFu;
      best = second; second = ~0ULL;
      if (best == ~0ULL){                          // top-2 exhausted: rescan own part
        #pragma unroll 4
        for (int j = 0; j < NPTS/512; ++j){
          const int q = tid + 512*j;
          const unsigned long long kk = ((unsigned long long)d2u[q]<<32)|(unsigned)q;
          if (kk < best){ second = best; best = kk; }
          else if (kk < second){ second = kk; }
        }
      }
    }
  }
  __syncthreads();   // nidx visible to staging
}

// ---------------------------------------------------------------------------
// EGNN per-scale (consumer phase 2), 512 threads: h = tid&127, 4 j-groups.
// ---------------------------------------------------------------------------
template<int KNB>
__device__ void egnn_scale512(const int isc, const int b, const int m, const int tid,
    const float* __restrict__ we1, const float* __restrict__ be1,
    const float* __restrict__ we2, const float* __restrict__ be2,
    const float* __restrict__ wxw, const float* __restrict__ bxw,
    const float* __restrict__ wh1, const float* __restrict__ bh1,
    const float* __restrict__ wh2, const float* __restrict__ bh2,
    const float* hi, const float (*hj)[NC], const float (*rel)[3], const float* d2s,
    float (*s1)[S1STR], float (*s2)[S1STR], float* coefs, float* aggs, float* t1,
    const float cx, const float cy, const float cz, float* __restrict__ out)
{
  constexpr int KH = KNB/4;
  const int h  = tid & 127;
  const int jg = tid >> 7;            // 0..3
  const int j0 = jg * KH;
  const float* W1 = we1 + (size_t)isc*(2*NC+1)*HH;
  const float* W2 = we2 + (size_t)isc*HH*HH;

  // ---- edge layer 1: [h_i, h_j, d2] @ we1 + be1, silu (h_i dot shared over j)
  float shi = be1[isc*HH + h];
  for (int r = 0; r < NC; ++r) shi += hi[r]*W1[r*HH + h];
  float acc[KH];
  #pragma unroll
  for (int jl = 0; jl < KH; ++jl) acc[jl] = shi;
  for (int r4 = 0; r4 < NC/4; ++r4){
    const float w0 = W1[(NC+4*r4+0)*HH+h];
    const float w1 = W1[(NC+4*r4+1)*HH+h];
    const float w2 = W1[(NC+4*r4+2)*HH+h];
    const float w3 = W1[(NC+4*r4+3)*HH+h];
    #pragma unroll
    for (int jl = 0; jl < KH; ++jl){
      const float4 v = *(const float4*)&hj[j0+jl][4*r4];
      acc[jl] += v.x*w0; acc[jl] += v.y*w1; acc[jl] += v.z*w2; acc[jl] += v.w*w3;
    }
  }
  {
    const float wd = W1[2*NC*HH + h];
    #pragma unroll
    for (int jl = 0; jl < KH; ++jl)
      s1[j0+jl][h] = silu_f(acc[jl] + d2s[j0+jl]*wd);
  }
  __syncthreads();

  // ---- edge layer 2
  float acc2[KH];
  { const float b2 = be2[isc*HH+h];
    #pragma unroll
    for (int jl=0;jl<KH;++jl) acc2[jl]=b2; }
  for (int r4 = 0; r4 < HH/4; ++r4){
    const float w0 = W2[(4*r4+0)*HH+h];
    const float w1 = W2[(4*r4+1)*HH+h];
    const float w2 = W2[(4*r4+2)*HH+h];
    const float w3 = W2[(4*r4+3)*HH+h];
    #pragma unroll
    for (int jl=0;jl<KH;++jl){
      const float4 v = *(const float4*)&s1[j0+jl][4*r4];
      acc2[jl]+=v.x*w0; acc2[jl]+=v.y*w1; acc2[jl]+=v.z*w2; acc2[jl]+=v.w*w3;
    }
  }
  #pragma unroll
  for (int jl=0;jl<KH;++jl) s2[j0+jl][h] = silu_f(acc2[jl]);
  __syncthreads();

  // ---- agg (tid<128) and coef per j (tid 128..128+KNB)
  if (tid < HH){
    float a = 0.f;
    #pragma unroll
    for (int j = 0; j < KNB; ++j) a += s2[j][tid];
    aggs[tid] = a;
  } else if (tid < HH + KNB){
    const int j = tid - HH;
    const float* WX = wxw + isc*HH;
    float c = 0.f;
    for (int r = 0; r < HH; ++r) c += s2[j][r]*WX[r];
    coefs[j] = c + bxw[isc];
  }
  __syncthreads();

  if (tid < 3){
    float s = 0.f;
    #pragma unroll
    for (int j = 0; j < KNB; ++j) s += rel[j][tid]*coefs[j];
    const float cc = (tid==0)?cx:((tid==1)?cy:cz);
    out[OUT1_OFF + ((size_t)(b*2+isc)*MCENT + m)*3 + tid] = cc + s*(1.0f/KNB);
  }
  if (tid < HH){
    const float* WH1 = wh1 + (size_t)isc*(NC+HH)*HH;
    float n = bh1[isc*HH + tid];
    for (int r = 0; r < NC; ++r) n += hi[r]*WH1[r*HH+tid];
    for (int r = 0; r < HH; ++r) n += aggs[r]*WH1[(NC+r)*HH+tid];
    t1[tid] = silu_f(n);
  }
  __syncthreads();
  if (tid < HH){
    const float* WH2 = wh2 + (size_t)isc*HH*HH;
    float v = bh2[isc*HH + tid];
    for (int r = 0; r < HH; ++r) v += t1[r]*WH2[r*HH+tid];
    out[OUT2_OFF + ((size_t)(b*2*HH) + isc*HH + tid)*MCENT + m] = v;
  }
  __syncthreads();   // before smem reuse by next scale / next item
}

// ---------------------------------------------------------------------------
// Consumer blocks 2..255: fence-free poll of pa[item]; the atomic word IS the
// data (winner index). Everything else derives from immutable inputs.
// ---------------------------------------------------------------------------
__device__ void consumer_block(const int tid,
    const float* __restrict__ xyz, const float* __restrict__ feat,
    const float* __restrict__ we1, const float* __restrict__ be1,
    const float* __restrict__ we2, const float* __restrict__ be2,
    const float* __restrict__ wxw, const float* __restrict__ bxw,
    const float* __restrict__ wh1, const float* __restrict__ bh1,
    const float* __restrict__ wh2, const float* __restrict__ bh2,
    unsigned* __restrict__ pa, float* __restrict__ out, char* smem)
{
  float (*s1)[S1STR] = (float (*)[S1STR])(smem + SM_S1);
  float (*s2)[S1STR] = (float (*)[S1STR])(smem + SM_S2);
  float (*hj)[NC]    = (float (*)[NC])(smem + SM_HJ);
  float* hi    = (float*)(smem + SM_HI);
  float (*rel)[3] = (float (*)[3])(smem + SM_REL);
  float* d2s   = (float*)(smem + SM_D2S);
  float* aggs  = (float*)(smem + SM_AGG);
  float* t1    = (float*)(smem + SM_T1);
  float* coefs = (float*)(smem + SM_COEF);
  int* nidx    = (int*)(smem + SM_NIDX);

  const int nitems = NB*MCENT;
  for (int item = (int)blockIdx.x - NB; item < nitems; item += (int)gridDim.x - NB){
    const int b = item >> 11;
    const int m = item & (MCENT-1);
    // fence-free wait: value SENT -> not ready; any other value is the payload.
    unsigned p = __hip_atomic_load(&pa[item], __ATOMIC_RELAXED, __HIP_MEMORY_SCOPE_AGENT);
    long spins = 0;
    while (p == SENT){
      __builtin_amdgcn_s_sleep(8);
      p = __hip_atomic_load(&pa[item], __ATOMIC_RELAXED, __HIP_MEMORY_SCOPE_AGENT);
      if (++spins > 2000000L) break;     // never expected; avoids infinite hang
    }
    if (p >= NPTS) p = 0;                // safety clamp (bail-out path only)

    const float* P = xyz + (size_t)b*NPTS*3;
    const float cx = P[p*3+0], cy = P[p*3+1], cz = P[p*3+2];
    if (tid == 0) out[OUT3_OFF + item] = (float)p;
    if (tid < 3)  out[OUT0_OFF + (size_t)item*3 + tid] = P[p*3+tid];

    knn512(b, cx, cy, cz, tid, xyz, smem);

    if (tid < NC) hi[tid] = feat[((size_t)b*NC + tid)*NPTS + p];
    if (tid < K2NN){
      const int q = nidx[tid];
      const float rx = cx - P[q*3+0];
      const float ry = cy - P[q*3+1];
      const float rz = cz - P[q*3+2];
      rel[tid][0]=rx; rel[tid][1]=ry; rel[tid][2]=rz;
      d2s[tid] = rx*rx + ry*ry + rz*rz;
    }
    {
      const int j  = tid >> 4;             // 0..31
      const int c0 = (tid & 15) * 4;
      const int q  = nidx[j];
      #pragma unroll
      for (int w = 0; w < 4; ++w)
        hj[j][c0+w] = feat[((size_t)b*NC + c0 + w)*NPTS + q];
    }
    __syncthreads();

    egnn_scale512<16>(0, b, m, tid, we1,be1,we2,be2,wxw,bxw,wh1,bh1,wh2,bh2,
                      hi, hj, rel, d2s, s1, s2, coefs, aggs, t1, cx, cy, cz, out);
    egnn_scale512<32>(1, b, m, tid, we1,be1,we2,be2,wxw,bxw,wh1,bh1,wh2,bh2,
                      hi, hj, rel, d2s, s1, s2, coefs, aggs, t1, cx, cy, cz, out);
  }
}

// ---------------------------------------------------------------------------
__global__ __launch_bounds__(512, 2) void fused_kernel(
    const float* __restrict__ xyz, const float* __restrict__ feat,
    const float* __restrict__ we1, const float* __restrict__ be1,
    const float* __restrict__ we2, const float* __restrict__ be2,
    const float* __restrict__ wxw, const float* __restrict__ bxw,
    const float* __restrict__ wh1, const float* __restrict__ bh1,
    const float* __restrict__ wh2, const float* __restrict__ bh2,
    unsigned* __restrict__ pa, float* __restrict__ out)
{
  __shared__ __align__(16) char smem[SM_SIZE];
  const int tid = threadIdx.x;
  if (blockIdx.x < NB){
    fps_block((int)blockIdx.x, tid, xyz, pa, smem);
  } else {
    consumer_block(tid, xyz, feat, we1,be1,we2,be2,wxw,bxw,wh1,bh1,wh2,bh2,
                   pa, out, smem);
  }
}

__global__ void init_kernel(unsigned* __restrict__ pa){
  const int i = threadIdx.x + blockIdx.x * blockDim.x;
  if (i < NB*MCENT) pa[i] = SENT;
}

// ---------------------------------------------------------------------------
extern "C" void kernel_launch(void* const* d_in, const int* in_sizes, int n_in,
                              void* d_out, int out_size, void* d_ws, size_t ws_size,
                              hipStream_t stream){
  const float* xyz = (const float*)d_in[0];
  const float* feat= (const float*)d_in[1];
  const float* we1 = (const float*)d_in[2];
  const float* be1 = (const float*)d_in[3];
  const float* we2 = (const float*)d_in[4];
  const float* be2 = (const float*)d_in[5];
  const float* wxw = (const float*)d_in[6];
  const float* bxw = (const float*)d_in[7];
  const float* wh1 = (const float*)d_in[8];
  const float* bh1 = (const float*)d_in[9];
  const float* wh2 = (const float*)d_in[10];
  const float* bh2 = (const float*)d_in[11];
  float* out = (float*)d_out;

  unsigned* pa = (unsigned*)d_ws;        // NB*MCENT publish slots (16 KB)

  init_kernel <<<dim3(8),    dim3(512), 0, stream>>>(pa);
  fused_kernel<<<dim3(GRID), dim3(512), 0, stream>>>(xyz, feat,
      we1, be1, we2, be2, wxw, bxw, wh1, bh1, wh2, bh2, pa, out);
}